// Round 7
// baseline (292.072 us; speedup 1.0000x reference)
//
#include <hip/hip_runtime.h>

// GraphConvolution: out[b,n,o] = sum_m adj[n,m] * (F[b,m,:] . W[o,:]) + b[o]
// B=8192, N=4, DIN=1024, DOUT=256.
//
// R8: 7 rounds of evidence: gconv is stuck at 60-91us with ALL pipes idle
// and ~6000 cyc/iteration of exposed latency regardless of barriers,
// occupancy, or load coalescing. Remaining in-loop suspects: the
// f2bf->ds_write->ds_read chain and vmcnt conflation (HBM A-prefetch and
// L2 B-loads share one counter; consuming B drains the 900-cyc A loads).
// Fix: move feat fp32->bf16 conversion to a streaming pre-pass (fprep)
// that writes feat in MFMA-FRAGMENT ORDER into d_ws (coalesced 2-KB wave
// reads, scattered 16-B writes -- writes don't stall). gconv is then pure
// registers: per kb, 4 coalesced A-chunk loads + 8 B-chunk loads + 16
// MFMAs. ZERO LDS / barriers / VALU-convert / ds ops; full unroll lets the
// scheduler hoist loads deep. Bit-identical numerics to R5-R7.
// New floor: fprep 192MB + gconv 96MB+L2 ~= 46us total vs fused 26us --
// accepted as the decisive structure experiment.

#define DIN 1024
#define DOUT 256
#define BM 32
#define KI 16  // DIN / 64

typedef __bf16 bf16x8 __attribute__((ext_vector_type(8)));
typedef float f32x4 __attribute__((ext_vector_type(4)));
typedef unsigned short u16x8 __attribute__((ext_vector_type(8)));

__device__ __forceinline__ unsigned short f2bf(float f) {
  union { float f; unsigned int u; } v;
  v.f = f;
  unsigned int u = v.u;
  u += 0x7fffu + ((u >> 16) & 1u);   // round-to-nearest-even
  return (unsigned short)(u >> 16);
}

__device__ __forceinline__ u16x8 pack8(f32x4 lo, f32x4 hi) {
  u16x8 r;
#pragma unroll
  for (int m = 0; m < 4; ++m) {
    r[m] = f2bf(lo[m]);
    r[4 + m] = f2bf(hi[m]);
  }
  return r;
}

// W [256x1024] fp32 -> bf16 in MFMA-fragment order (R6-verified).
// Chunk c = ((g*16 + kb)*2 + ks)*4 + j  (512 chunks x 1 KB);
// lane l holds W[g*64+j*16+(l&15)][kb*64+ks*32+(l>>4)*8 .. +8].
__global__ __launch_bounds__(256) void wprep_kernel(
    const float* __restrict__ W, unsigned short* __restrict__ ws) {
  const int t = blockIdx.x * 256 + threadIdx.x;  // 32768 threads
  const int lane = t & 63;
  const int j = (t >> 6) & 3;
  const int ks = (t >> 8) & 1;
  const int kb = (t >> 9) & 15;
  const int g = (t >> 13) & 3;
  const int col = g * 64 + j * 16 + (lane & 15);
  const int k0 = kb * 64 + ks * 32 + (lane >> 4) * 8;
  const f32x4* src = (const f32x4*)(W + (size_t)col * DIN + k0);
  f32x4 a = src[0], b = src[1];
  *(u16x8*)(ws + (size_t)t * 8) = pack8(a, b);
}

// feat [32768 x 1024] fp32 -> bf16 in MFMA-fragment order.
// Chunk c = m*64 + (i*16 + kb)*2 + ks  (m = 32-row block, i = 16-row half);
// lane l holds feat[m*32+i*16+(l&15)][kb*64+ks*32+(l>>4)*8 .. +8].
// Read side coalesced (wave reads 2 KB contiguous); write side scattered
// 16-B stores (fire-and-forget).
__global__ __launch_bounds__(256) void fprep_kernel(
    const float* __restrict__ feat, unsigned short* __restrict__ fs) {
  const int t = blockIdx.x * 256 + threadIdx.x;  // 4,194,304 threads
  const int k8 = t & 127;                        // 8-float chunk within row
  const int row = t >> 7;
  const f32x4* src = (const f32x4*)(feat + (size_t)row * DIN + k8 * 8);
  f32x4 a = src[0], b = src[1];
  const int m = row >> 5;
  const int i = (row >> 4) & 1;
  const int rl = row & 15;
  const int kb = k8 >> 3;
  const int ks = (k8 >> 2) & 1;
  const int q = k8 & 3;
  const size_t off =
      (((size_t)m * 64 + (i * 16 + kb) * 2 + ks) * 512) + (q * 16 + rl) * 8;
  *(u16x8*)(fs + off) = pack8(a, b);
}

__global__ __launch_bounds__(256, 3) void gconv_kernel(
    const float* __restrict__ adj, const unsigned short* __restrict__ fimg,
    const unsigned short* __restrict__ wimg, const float* __restrict__ bias,
    float* __restrict__ out) {
  const int tid = threadIdx.x;
  const int bM = blockIdx.x * BM;

  const int lane = tid & 63;
  const int wid = tid >> 6;
  const int wc = wid * 64;
  const int rl = lane & 15;
  const int q = lane >> 4;

  // fragment images: every load below is base + lane*16 B (one coalesced
  // 1-KB wave transaction).
  const unsigned short* ap = fimg + (size_t)blockIdx.x * 64 * 512 + lane * 8;
  const unsigned short* bp = wimg + (size_t)wid * 128 * 512 + lane * 8;

  f32x4 acc[2][4];
#pragma unroll
  for (int i = 0; i < 2; ++i)
#pragma unroll
    for (int j = 0; j < 4; ++j) acc[i][j] = f32x4{0.f, 0.f, 0.f, 0.f};

#pragma unroll
  for (int kb = 0; kb < KI; ++kb) {
    bf16x8 af[2][2];
#pragma unroll
    for (int i = 0; i < 2; ++i)
#pragma unroll
      for (int ks = 0; ks < 2; ++ks)
        af[i][ks] = *(const bf16x8*)(ap + ((i * 16 + kb) * 2 + ks) * 512);

    bf16x8 bfr[2][4];
#pragma unroll
    for (int ks = 0; ks < 2; ++ks)
#pragma unroll
      for (int j = 0; j < 4; ++j)
        bfr[ks][j] = *(const bf16x8*)(bp + ((kb * 2 + ks) * 4 + j) * 512);

#pragma unroll
    for (int ks = 0; ks < 2; ++ks)
#pragma unroll
      for (int i = 0; i < 2; ++i)
#pragma unroll
        for (int j = 0; j < 4; ++j)
          acc[i][j] = __builtin_amdgcn_mfma_f32_16x16x32_bf16(
              af[i][ks], bfr[ks][j], acc[i][j], 0, 0, 0);
  }

  // epilogue: adj 4x4 mix (regs = rows 4q..4q+3 of one batch) + bias
  float am[16];
#pragma unroll
  for (int i = 0; i < 16; ++i) am[i] = adj[i];  // uniform -> scalar loads

  float bv[4];
#pragma unroll
  for (int j = 0; j < 4; ++j) bv[j] = bias[wc + j * 16 + rl];

#pragma unroll
  for (int i = 0; i < 2; ++i) {
    const size_t rowbase = (size_t)(bM + i * 16 + q * 4);
#pragma unroll
    for (int j = 0; j < 4; ++j) {
      const int col = wc + j * 16 + rl;
      float* op = out + rowbase * DOUT + col;
      f32x4 g = acc[i][j];
#pragma unroll
      for (int n = 0; n < 4; ++n) {
        op[(size_t)n * DOUT] = am[n * 4 + 0] * g[0] + am[n * 4 + 1] * g[1] +
                               am[n * 4 + 2] * g[2] + am[n * 4 + 3] * g[3] +
                               bv[j];
      }
    }
  }
}

extern "C" void kernel_launch(void* const* d_in, const int* in_sizes, int n_in,
                              void* d_out, int out_size, void* d_ws,
                              size_t ws_size, hipStream_t stream) {
  const float* adj = (const float*)d_in[0];
  const float* feat = (const float*)d_in[1];
  const float* W = (const float*)d_in[2];
  const float* bias = (const float*)d_in[3];
  float* out = (float*)d_out;
  unsigned short* ws = (unsigned short*)d_ws;
  unsigned short* wimg = ws;                 // 512 KB fragment-ordered W
  unsigned short* fimg = ws + 262144;        // 64 MiB fragment-ordered feat

  wprep_kernel<<<128, 256, 0, stream>>>(W, wimg);
  fprep_kernel<<<16384, 256, 0, stream>>>(feat, fimg);
  gconv_kernel<<<8192 * 4 / BM, 256, 0, stream>>>(adj, fimg, wimg, bias, out);
}

// Round 8
// 264.311 us; speedup vs baseline: 1.1050x; 1.1050x over previous
//
#include <hip/hip_runtime.h>

// GraphConvolution: out[b,n,o] = sum_m adj[n,m] * (F[b,m,:] . W[o,:]) + b[o]
// B=8192, N=4, DIN=1024, DOUT=256.
//
// R9: R8 proved the pure-register MFMA loop runs ~32us (no LDS, no
// barriers, coalesced fragment loads) -- the in-loop staging chain was the
// ~6000cyc/iter wall. But the separate fprep pass cost 100us (256-B-stride
// 16-B stores). Fuse A back in WITHOUT reintroducing LDS: load feat fp32
// directly into MFMA fragment registers (16-rows x 16-B/lane pattern; only
// full 64-B lines touched, pairs of loads cover lines completely, 4 waves
// share rows via L1) and convert in-loop with compiler __bf16 casts
// (clang emits packed v_cvt_pk_bf16_f32; ~64 VALU cyc/kb vs 80 MFMA cyc).
// Differences vs failed R4: B from the coalesced fragment image (R4's
// killer was 16-way B scatter), grid 1024, cheap cvt. No fprep. Traffic =
// minimal 128MB feat read + 32MB out write + L2-resident B.

#define DIN 1024
#define DOUT 256
#define BM 32
#define KI 16  // DIN / 64

typedef __bf16 bf16x8 __attribute__((ext_vector_type(8)));
typedef float f32x4 __attribute__((ext_vector_type(4)));
typedef unsigned short u16x8 __attribute__((ext_vector_type(8)));

__device__ __forceinline__ unsigned short f2bf(float f) {
  union { float f; unsigned int u; } v;
  v.f = f;
  unsigned int u = v.u;
  u += 0x7fffu + ((u >> 16) & 1u);   // round-to-nearest-even
  return (unsigned short)(u >> 16);
}

// RTNE via HW cvt (clang packs pairs into v_cvt_pk_bf16_f32)
__device__ __forceinline__ bf16x8 cvt8(f32x4 lo, f32x4 hi) {
  bf16x8 r;
#pragma unroll
  for (int m = 0; m < 4; ++m) {
    r[m] = (__bf16)lo[m];
    r[4 + m] = (__bf16)hi[m];
  }
  return r;
}

// W [256x1024] fp32 -> bf16 in MFMA-fragment order (R6-verified).
// Chunk c = ((g*16 + kb)*2 + ks)*4 + j  (512 chunks x 1 KB);
// lane l holds W[g*64+j*16+(l&15)][kb*64+ks*32+(l>>4)*8 .. +8].
__global__ __launch_bounds__(256) void wprep_kernel(
    const float* __restrict__ W, unsigned short* __restrict__ ws) {
  const int t = blockIdx.x * 256 + threadIdx.x;  // 32768 threads
  const int lane = t & 63;
  const int j = (t >> 6) & 3;
  const int ks = (t >> 8) & 1;
  const int kb = (t >> 9) & 15;
  const int g = (t >> 13) & 3;
  const int col = g * 64 + j * 16 + (lane & 15);
  const int k0 = kb * 64 + ks * 32 + (lane >> 4) * 8;
  const f32x4* src = (const f32x4*)(W + (size_t)col * DIN + k0);
  f32x4 a = src[0], b = src[1];
  u16x8 pk;
#pragma unroll
  for (int m = 0; m < 4; ++m) {
    pk[m] = f2bf(a[m]);
    pk[4 + m] = f2bf(b[m]);
  }
  *(u16x8*)(ws + (size_t)t * 8) = pk;
}

__global__ __launch_bounds__(256, 3) void gconv_kernel(
    const float* __restrict__ adj, const float* __restrict__ feat,
    const unsigned short* __restrict__ wimg, const float* __restrict__ bias,
    float* __restrict__ out) {
  const int tid = threadIdx.x;
  const int bM = blockIdx.x * BM;

  const int lane = tid & 63;
  const int wid = tid >> 6;
  const int wc = wid * 64;
  const int rl = lane & 15;
  const int q = lane >> 4;
  const int q8 = q * 8;

  // B fragment image: every load is base + lane*16 B (one 1-KB wave tx)
  const unsigned short* bp = wimg + (size_t)wid * 128 * 512 + lane * 8;
  // A fragment position: row = bM + i*16 + rl, k = kb*64 + ks*32 + q8
  const float* ap = feat + (size_t)(bM + rl) * DIN + q8;

  f32x4 acc[2][4];
#pragma unroll
  for (int i = 0; i < 2; ++i)
#pragma unroll
    for (int j = 0; j < 4; ++j) acc[i][j] = f32x4{0.f, 0.f, 0.f, 0.f};

  // A fp32 fragment regs, double-buffered one kb ahead
  f32x4 pa[2][2][2];  // [i][ks][half]
#pragma unroll
  for (int i = 0; i < 2; ++i)
#pragma unroll
    for (int ks = 0; ks < 2; ++ks)
#pragma unroll
      for (int h = 0; h < 2; ++h)
        pa[i][ks][h] =
            *(const f32x4*)(ap + (size_t)i * 16 * DIN + ks * 32 + h * 4);

#pragma unroll
  for (int kb = 0; kb < KI; ++kb) {
    // B fragments: coalesced loads from the L2-resident image
    bf16x8 bfr[2][4];
#pragma unroll
    for (int ks = 0; ks < 2; ++ks)
#pragma unroll
      for (int j = 0; j < 4; ++j)
        bfr[ks][j] = *(const bf16x8*)(bp + ((kb * 2 + ks) * 4 + j) * 512);

    // convert current A regs (frees pa for the next prefetch)
    bf16x8 af[2][2];
#pragma unroll
    for (int i = 0; i < 2; ++i)
#pragma unroll
      for (int ks = 0; ks < 2; ++ks)
        af[i][ks] = cvt8(pa[i][ks][0], pa[i][ks][1]);

    // prefetch next kb of A (HBM latency hides under cvt+MFMA)
    if (kb + 1 < KI) {
#pragma unroll
      for (int i = 0; i < 2; ++i)
#pragma unroll
        for (int ks = 0; ks < 2; ++ks)
#pragma unroll
          for (int h = 0; h < 2; ++h)
            pa[i][ks][h] = *(const f32x4*)(ap + (size_t)i * 16 * DIN +
                                           (kb + 1) * 64 + ks * 32 + h * 4);
    }

#pragma unroll
    for (int ks = 0; ks < 2; ++ks)
#pragma unroll
      for (int i = 0; i < 2; ++i)
#pragma unroll
        for (int j = 0; j < 4; ++j)
          acc[i][j] = __builtin_amdgcn_mfma_f32_16x16x32_bf16(
              af[i][ks], bfr[ks][j], acc[i][j], 0, 0, 0);
  }

  // epilogue: adj 4x4 mix (regs = rows 4q..4q+3 of one batch) + bias
  float am[16];
#pragma unroll
  for (int i = 0; i < 16; ++i) am[i] = adj[i];  // uniform -> scalar loads

  float bv[4];
#pragma unroll
  for (int j = 0; j < 4; ++j) bv[j] = bias[wc + j * 16 + rl];

#pragma unroll
  for (int i = 0; i < 2; ++i) {
    const size_t rowbase = (size_t)(bM + i * 16 + q * 4);
#pragma unroll
    for (int j = 0; j < 4; ++j) {
      const int col = wc + j * 16 + rl;
      float* op = out + rowbase * DOUT + col;
      f32x4 g = acc[i][j];
#pragma unroll
      for (int n = 0; n < 4; ++n) {
        op[(size_t)n * DOUT] = am[n * 4 + 0] * g[0] + am[n * 4 + 1] * g[1] +
                               am[n * 4 + 2] * g[2] + am[n * 4 + 3] * g[3] +
                               bv[j];
      }
    }
  }
}

extern "C" void kernel_launch(void* const* d_in, const int* in_sizes, int n_in,
                              void* d_out, int out_size, void* d_ws,
                              size_t ws_size, hipStream_t stream) {
  const float* adj = (const float*)d_in[0];
  const float* feat = (const float*)d_in[1];
  const float* W = (const float*)d_in[2];
  const float* bias = (const float*)d_in[3];
  float* out = (float*)d_out;
  unsigned short* ws = (unsigned short*)d_ws;  // 512 KB fragment-ordered W

  wprep_kernel<<<128, 256, 0, stream>>>(W, ws);
  gconv_kernel<<<8192 * 4 / BM, 256, 0, stream>>>(adj, feat, ws, bias, out);
}

// Round 10
// 230.271 us; speedup vs baseline: 1.2684x; 1.1478x over previous
//
#include <hip/hip_runtime.h>

// GraphConvolution: out[b,n,o] = sum_m adj[n,m] * (F[b,m,:] . W[o,:]) + b[o]
// B=8192, N=4, DIN=1024, DOUT=256.
//
// R10 (resubmit; prior round hit GPUAcquisitionTimeout, never measured):
// 9 rounds of evidence: any fragment load that scatters across cache
// lines costs 91-137us; the all-coalesced pure-register MFMA loop (R8) runs
// ~32us; R8's only flaw was the 100us fprep pre-pass (write-scattered).
// Fix: one-shot IN-BLOCK A transpose. Each block coalesced-reads its whole
// 32x1024 fp32 A-tile once, converts (f2bf, bit-identical to all passing
// rounds), ds_writes into a 64-KB LDS image in R8's HW-verified fragment-
// chunk order, ONE __syncthreads, then runs R8's pure-register loop with
// conflict-free ds_read_b128 (lane l reads chunk*1024 + l*16: contiguous)
// + coalesced 1-KB B loads from the L2-resident W image + 16 MFMAs/kb.
// No in-loop barriers/cvt/staging. feat read once (128MB minimal).
// LDS 64KB -> 2 blocks/CU; cross-block wave overlap hides staging.

#define DIN 1024
#define DOUT 256
#define BM 32
#define KI 16  // DIN / 64

typedef __bf16 bf16x8 __attribute__((ext_vector_type(8)));
typedef float f32x4 __attribute__((ext_vector_type(4)));
typedef unsigned short u16x8 __attribute__((ext_vector_type(8)));

__device__ __forceinline__ unsigned short f2bf(float f) {
  union { float f; unsigned int u; } v;
  v.f = f;
  unsigned int u = v.u;
  u += 0x7fffu + ((u >> 16) & 1u);   // round-to-nearest-even
  return (unsigned short)(u >> 16);
}

__device__ __forceinline__ u16x8 pack8(f32x4 lo, f32x4 hi) {
  u16x8 r;
#pragma unroll
  for (int m = 0; m < 4; ++m) {
    r[m] = f2bf(lo[m]);
    r[4 + m] = f2bf(hi[m]);
  }
  return r;
}

// W [256x1024] fp32 -> bf16 in MFMA-fragment order (R6-verified).
// Chunk c = ((g*16 + kb)*2 + ks)*4 + j  (512 chunks x 1 KB);
// lane l holds W[g*64+j*16+(l&15)][kb*64+ks*32+(l>>4)*8 .. +8].
__global__ __launch_bounds__(256) void wprep_kernel(
    const float* __restrict__ W, unsigned short* __restrict__ ws) {
  const int t = blockIdx.x * 256 + threadIdx.x;  // 32768 threads
  const int lane = t & 63;
  const int j = (t >> 6) & 3;
  const int ks = (t >> 8) & 1;
  const int kb = (t >> 9) & 15;
  const int g = (t >> 13) & 3;
  const int col = g * 64 + j * 16 + (lane & 15);
  const int k0 = kb * 64 + ks * 32 + (lane >> 4) * 8;
  const f32x4* src = (const f32x4*)(W + (size_t)col * DIN + k0);
  f32x4 a = src[0], b = src[1];
  *(u16x8*)(ws + (size_t)t * 8) = pack8(a, b);
}

__global__ __launch_bounds__(256, 2) void gconv_kernel(
    const float* __restrict__ adj, const float* __restrict__ feat,
    const unsigned short* __restrict__ wimg, const float* __restrict__ bias,
    float* __restrict__ out) {
  // A-tile in fragment-chunk order: 64 chunks x 512 halfs = 64 KB.
  // Chunk c = (i*16 + kb)*2 + ks; within a chunk, lane l holds
  // feat[bM + i*16 + (l&15)][kb*64 + ks*32 + (l>>4)*8 .. +8]  (R8-verified).
  __shared__ __align__(16) unsigned short sA[64 * 512];

  const int tid = threadIdx.x;
  const int bM = blockIdx.x * BM;

  const int lane = tid & 63;
  const int wid = tid >> 6;
  const int wc = wid * 64;
  const int rl = lane & 15;
  const int q = lane >> 4;

  // ---- one-shot staging: coalesced fp32 read -> f2bf -> fragment ds_write
  {
    const int r = tid >> 3;        // 0..31 (row within tile)
    const int c8 = tid & 7;        // 8-float chunk within a 64-float K-block
    const int i_ = r >> 4;
    const int rls = r & 15;
    const int kss = c8 >> 2;
    const int qs = c8 & 3;
    const float* src = feat + (size_t)(bM + r) * DIN + c8 * 8;
    unsigned short* dst = sA + (qs * 16 + rls) * 8;
#pragma unroll
    for (int kc = 0; kc < KI; ++kc) {
      f32x4 a = *(const f32x4*)(src + kc * 64);
      f32x4 b = *(const f32x4*)(src + kc * 64 + 4);
      *(u16x8*)(dst + ((i_ * 16 + kc) * 2 + kss) * 512) = pack8(a, b);
    }
  }

  f32x4 acc[2][4];
#pragma unroll
  for (int i = 0; i < 2; ++i)
#pragma unroll
    for (int j = 0; j < 4; ++j) acc[i][j] = f32x4{0.f, 0.f, 0.f, 0.f};

  __syncthreads();

  // ---- pure-register MFMA loop (R8 structure; A from LDS, conflict-free)
  const unsigned short* bp = wimg + (size_t)wid * 128 * 512 + lane * 8;
  const unsigned short* apl = sA + lane * 8;

#pragma unroll
  for (int kb = 0; kb < KI; ++kb) {
    bf16x8 bfr[2][4];
#pragma unroll
    for (int ks = 0; ks < 2; ++ks)
#pragma unroll
      for (int j = 0; j < 4; ++j)
        bfr[ks][j] = *(const bf16x8*)(bp + ((kb * 2 + ks) * 4 + j) * 512);

    bf16x8 af[2][2];
#pragma unroll
    for (int i = 0; i < 2; ++i)
#pragma unroll
      for (int ks = 0; ks < 2; ++ks)
        af[i][ks] = *(const bf16x8*)(apl + ((i * 16 + kb) * 2 + ks) * 512);

#pragma unroll
    for (int ks = 0; ks < 2; ++ks)
#pragma unroll
      for (int i = 0; i < 2; ++i)
#pragma unroll
        for (int j = 0; j < 4; ++j)
          acc[i][j] = __builtin_amdgcn_mfma_f32_16x16x32_bf16(
              af[i][ks], bfr[ks][j], acc[i][j], 0, 0, 0);
  }

  // ---- epilogue: adj 4x4 mix (regs = rows 4q..4q+3 of one batch) + bias
  float am[16];
#pragma unroll
  for (int i = 0; i < 16; ++i) am[i] = adj[i];  // uniform -> scalar loads

  float bv[4];
#pragma unroll
  for (int j = 0; j < 4; ++j) bv[j] = bias[wc + j * 16 + rl];

#pragma unroll
  for (int i = 0; i < 2; ++i) {
    const size_t rowbase = (size_t)(bM + i * 16 + q * 4);
#pragma unroll
    for (int j = 0; j < 4; ++j) {
      const int col = wc + j * 16 + rl;
      float* op = out + rowbase * DOUT + col;
      f32x4 g = acc[i][j];
#pragma unroll
      for (int n = 0; n < 4; ++n) {
        op[(size_t)n * DOUT] = am[n * 4 + 0] * g[0] + am[n * 4 + 1] * g[1] +
                               am[n * 4 + 2] * g[2] + am[n * 4 + 3] * g[3] +
                               bv[j];
      }
    }
  }
}

extern "C" void kernel_launch(void* const* d_in, const int* in_sizes, int n_in,
                              void* d_out, int out_size, void* d_ws,
                              size_t ws_size, hipStream_t stream) {
  const float* adj = (const float*)d_in[0];
  const float* feat = (const float*)d_in[1];
  const float* W = (const float*)d_in[2];
  const float* bias = (const float*)d_in[3];
  float* out = (float*)d_out;
  unsigned short* ws = (unsigned short*)d_ws;  // 512 KB fragment-ordered W

  wprep_kernel<<<128, 256, 0, stream>>>(W, ws);
  gconv_kernel<<<8192 * 4 / BM, 256, 0, stream>>>(adj, feat, ws, bias, out);
}